// Round 1
// 207.717 us; speedup vs baseline: 1.0010x; 1.0010x over previous
//
#include <hip/hip_runtime.h>

// Shapes: tarsent [8,512,512] f32, tar_func [8,512] i32,
//         refsent [8,32,256,512] f32, ref_func [8,32,256] i32.
// Output flat-concat f32 (masks as 0.0/1.0):
//   tar_aug[8,5,512]@0  tar_aug_mask[8,5]@20480  ref_aug[8,32,5,512]@20520
//   ref_aug_mask[8,32,5]@675880  tarpaper[8,512]@677160  tar_mask2[8]@681256
//   refpaper[8,32,512]@681264  ref_mask2[8,32]@812336   total 812592

#define H      512
#define HV     128
#define NL     5
#define BIGF   1e11f
#define CHUNK  64          // sentences per stage-1 block

#define OFF_TAR_AUG       0
#define OFF_TAR_AUG_MASK  20480
#define OFF_REF_AUG       20520
#define OFF_REF_AUG_MASK  675880
#define OFF_TARPAPER      677160
#define OFF_TAR_MASK2     681256
#define OFF_REFPAPER      681264
#define OFF_REF_MASK2     812336

#define NCHUNK_REF 4       // 256 / 64
#define NCHUNK_TAR 8       // 512 / 64
#define NBLK_REF   1024    // 256 segs * 4
#define NBLK1      1088    // + 8 segs * 8
#define WSUM_ELEMS ((size_t)NBLK1 * NL * H)      // 11.1 MB
#define WCNT_OFF_B (WSUM_ELEMS * 4)
#define WS_NEED    (WCNT_OFF_B + (size_t)NBLK1 * NL * 4)

__device__ inline float4 f4add(float4 a, float4 b) {
    a.x += b.x; a.y += b.y; a.z += b.z; a.w += b.w; return a;
}
__device__ inline float4 f4scale(float4 a, float s) {
    a.x *= s; a.y *= s; a.z *= s; a.w *= s; return a;
}
__device__ inline float4 f4fma(float w, float4 v, float4 a) {
    a.x = fmaf(w, v.x, a.x); a.y = fmaf(w, v.y, a.y);
    a.z = fmaf(w, v.z, a.z); a.w = fmaf(w, v.w, a.w); return a;
}

// ---------------- Stage 1: per-(segment,chunk) partial label sums ----------
// Ballot-compacts non-pad rows (label!=0) into (absolute row, label) pairs,
// then each thread streams its rows DIRECTLY from global with float4 loads —
// no LDS staging, no per-chunk vmcnt(0) drain, no loop barriers. Streaming
// reduction has zero reuse, so staging was pure latency overhead.
__global__ __launch_bounds__(256) void emenc_stage1(
    const float* __restrict__ tar_state, const int* __restrict__ tar_func,
    const float* __restrict__ ref_state, const int* __restrict__ ref_func,
    float* __restrict__ wsum, int* __restrict__ wcnt)
{
    __shared__ float4 spart[HV * NL];    // 10 KB phase-combine
    __shared__ int    crow[CHUNK];       // compacted ABSOLUTE row indices
    __shared__ int    clab[CHUNK];       // compacted labels
    __shared__ int    scnt5[NL];
    __shared__ int    sm;

    const int b = blockIdx.x;
    const float* state;
    const int*   func;
    int s0;
    if (b < NBLK_REF) {
        const int seg = b >> 2, ch = b & 3;
        state = ref_state + (size_t)seg * 256 * H;
        func  = ref_func  + seg * 256;
        s0    = ch * CHUNK;
    } else {
        const int q = b - NBLK_REF;
        const int seg = q >> 3, ch = q & 7;
        state = tar_state + (size_t)seg * 512 * H;
        func  = tar_func  + seg * 512;
        s0    = ch * CHUNK;
    }

    const int tid = threadIdx.x;

    // Wave 0 (tids 0..63, exactly one wave): label counts + compaction via
    // ballots. CHUNK == wavefront size == 64.
    if (tid < CHUNK) {
        const int l = func[s0 + tid];
        #pragma unroll
        for (int q = 1; q <= NL; ++q) {
            const unsigned long long mq = __ballot(l == q);
            if (tid == 0) scnt5[q - 1] = (int)__popcll(mq);
        }
        const unsigned long long mask = __ballot(l != 0);
        if (l != 0) {
            const int pos = (int)__popcll(mask & ((1ull << tid) - 1ull));
            crow[pos] = s0 + tid;      // absolute row within segment
            clab[pos] = l;
        }
        if (tid == 0) sm = (int)__popcll(mask);
    }
    __syncthreads();

    const int m     = sm;                 // non-pad rows in this chunk
    const int col   = tid & (HV - 1);     // float4 column 0..127
    const int phase = tid >> 7;           // 0/1: even/odd compact indices

    float4 a1 = {0,0,0,0}, a2 = {0,0,0,0}, a3 = {0,0,0,0},
           a4 = {0,0,0,0}, a5 = {0,0,0,0};

    // Direct-global streaming: each thread handles compact rows
    // phase, phase+2, ... Unroll keeps 4 float4 loads in flight per thread;
    // ~8 blocks/CU of TLP hides the rest of the HBM latency.
    #pragma unroll 4
    for (int r = phase; r < m; r += 2) {
        const int row = crow[r];
        const int l   = clab[r];
        const float4 v = *(const float4*)(state + ((size_t)row << 9) + col * 4);
        a1 = f4fma((l == 1) ? 1.0f : 0.0f, v, a1);
        a2 = f4fma((l == 2) ? 1.0f : 0.0f, v, a2);
        a3 = f4fma((l == 3) ? 1.0f : 0.0f, v, a3);
        a4 = f4fma((l == 4) ? 1.0f : 0.0f, v, a4);
        a5 = f4fma((l == 5) ? 1.0f : 0.0f, v, a5);
    }

    // Phase combine + write partials.
    if (phase == 1) {
        spart[col * NL + 0] = a1;
        spart[col * NL + 1] = a2;
        spart[col * NL + 2] = a3;
        spart[col * NL + 3] = a4;
        spart[col * NL + 4] = a5;
    }
    __syncthreads();

    if (phase == 0) {
        a1 = f4add(a1, spart[col * NL + 0]);
        a2 = f4add(a2, spart[col * NL + 1]);
        a3 = f4add(a3, spart[col * NL + 2]);
        a4 = f4add(a4, spart[col * NL + 3]);
        a5 = f4add(a5, spart[col * NL + 4]);

        float* wb = wsum + (size_t)b * NL * H;
        ((float4*)(wb + 0 * H))[col] = a1;
        ((float4*)(wb + 1 * H))[col] = a2;
        ((float4*)(wb + 2 * H))[col] = a3;
        ((float4*)(wb + 3 * H))[col] = a4;
        ((float4*)(wb + 4 * H))[col] = a5;
    }
    if (tid < NL) wcnt[b * NL + tid] = scnt5[tid];
}

// ---------------- Stage 2: one block per (segment, role) ------------------
__global__ __launch_bounds__(128) void emenc_stage2(
    const float* __restrict__ wsum, const int* __restrict__ wcnt,
    float* __restrict__ out)
{
    const int bb   = blockIdx.x;
    const int seg  = bb / 6;
    const int role = bb - seg * 6;

    int nch, wb0;
    float *aug, *augmask, *paper, *mask2;
    if (seg < 256) {
        nch = NCHUNK_REF; wb0 = seg * NCHUNK_REF;
        aug     = out + OFF_REF_AUG      + (size_t)seg * NL * H;
        augmask = out + OFF_REF_AUG_MASK + seg * NL;
        paper   = out + OFF_REFPAPER     + (size_t)seg * H;
        mask2   = out + OFF_REF_MASK2    + seg;
    } else {
        const int q = seg - 256;
        nch = NCHUNK_TAR; wb0 = NBLK_REF + q * NCHUNK_TAR;
        aug     = out + OFF_TAR_AUG      + (size_t)q * NL * H;
        augmask = out + OFF_TAR_AUG_MASK + q * NL;
        paper   = out + OFF_TARPAPER     + (size_t)q * H;
        mask2   = out + OFF_TAR_MASK2    + q;
    }

    const int col = threadIdx.x;

    if (role < NL) {
        int c = 0;
        for (int ch = 0; ch < nch; ch++) c += wcnt[(wb0 + ch) * NL + role];
        float4 s = {0,0,0,0};
        for (int ch = 0; ch < nch; ch++)
            s = f4add(s, ((const float4*)(wsum + (size_t)(wb0 + ch) * NL * H
                                          + (size_t)role * H))[col]);
        const float inv = 1.0f / (c > 0 ? (float)c : BIGF);
        ((float4*)(aug + (size_t)role * H))[col] = f4scale(s, inv);
        if (col == 0) augmask[role] = c > 0 ? 1.0f : 0.0f;
    } else {
        int ct = 0;
        for (int ch = 0; ch < nch; ch++) {
            #pragma unroll
            for (int l = 0; l < NL; l++) ct += wcnt[(wb0 + ch) * NL + l];
        }
        float4 t = {0,0,0,0};
        for (int ch = 0; ch < nch; ch++) {
            const float4* wb = (const float4*)(wsum + (size_t)(wb0 + ch) * NL * H);
            #pragma unroll
            for (int l = 0; l < NL; l++) t = f4add(t, wb[l * HV + col]);
        }
        ((float4*)paper)[col] = f4scale(t, 1.0f / (ct > 0 ? (float)ct : BIGF));
        if (col == 0) mask2[0] = ct > 0 ? 1.0f : 0.0f;
    }
}

// ---------------- Fallback (single-stage) if ws too small ------------------
__global__ __launch_bounds__(256) void emenc_single(
    const float* __restrict__ tar_state, const int* __restrict__ tar_func,
    const float* __restrict__ ref_state, const int* __restrict__ ref_func,
    float* __restrict__ out)
{
    __shared__ int    sfunc[512];
    __shared__ float4 spart[HV * NL];
    __shared__ int    scnt[NL];

    const int b = blockIdx.x;
    const float* state;
    const int*   func;
    int S;
    float *aug, *augmask, *paper, *mask2;

    if (b < 256) {
        state   = ref_state + (size_t)b * 256 * H;
        func    = ref_func  + b * 256;
        S       = 256;
        aug     = out + OFF_REF_AUG      + (size_t)b * NL * H;
        augmask = out + OFF_REF_AUG_MASK + b * NL;
        paper   = out + OFF_REFPAPER     + (size_t)b * H;
        mask2   = out + OFF_REF_MASK2    + b;
    } else {
        const int q = b - 256;
        state   = tar_state + (size_t)q * 512 * H;
        func    = tar_func  + q * 512;
        S       = 512;
        aug     = out + OFF_TAR_AUG      + (size_t)q * NL * H;
        augmask = out + OFF_TAR_AUG_MASK + q * NL;
        paper   = out + OFF_TARPAPER     + (size_t)q * H;
        mask2   = out + OFF_TAR_MASK2    + q;
    }

    const int tid = threadIdx.x;
    for (int i = tid; i < S; i += 256) sfunc[i] = func[i];
    __syncthreads();

    const int col   = tid & (HV - 1);
    const int phase = tid >> 7;

    float4 a1 = {0,0,0,0}, a2 = {0,0,0,0}, a3 = {0,0,0,0},
           a4 = {0,0,0,0}, a5 = {0,0,0,0};

    for (int s = phase; s < S; s += 2) {
        float4 v = ((const float4*)(state + (size_t)s * H))[col];
        const int l = sfunc[s];
        a1 = f4fma((l == 1) ? 1.0f : 0.0f, v, a1);
        a2 = f4fma((l == 2) ? 1.0f : 0.0f, v, a2);
        a3 = f4fma((l == 3) ? 1.0f : 0.0f, v, a3);
        a4 = f4fma((l == 4) ? 1.0f : 0.0f, v, a4);
        a5 = f4fma((l == 5) ? 1.0f : 0.0f, v, a5);
    }

    if (phase == 1) {
        spart[col * NL + 0] = a1;
        spart[col * NL + 1] = a2;
        spart[col * NL + 2] = a3;
        spart[col * NL + 3] = a4;
        spart[col * NL + 4] = a5;
    }
    if (tid < NL) {
        int c = 0;
        for (int i = 0; i < S; ++i) c += (sfunc[i] == tid + 1) ? 1 : 0;
        scnt[tid] = c;
    }
    __syncthreads();

    if (phase == 0) {
        a1 = f4add(a1, spart[col * NL + 0]);
        a2 = f4add(a2, spart[col * NL + 1]);
        a3 = f4add(a3, spart[col * NL + 2]);
        a4 = f4add(a4, spart[col * NL + 3]);
        a5 = f4add(a5, spart[col * NL + 4]);

        const int c1 = scnt[0], c2 = scnt[1], c3 = scnt[2],
                  c4 = scnt[3], c5 = scnt[4];
        float4 t  = f4add(f4add(f4add(a1, a2), f4add(a3, a4)), a5);
        const int ct = c1 + c2 + c3 + c4 + c5;

        ((float4*)(aug + 0 * H))[col] = f4scale(a1, 1.0f / (c1 > 0 ? (float)c1 : BIGF));
        ((float4*)(aug + 1 * H))[col] = f4scale(a2, 1.0f / (c2 > 0 ? (float)c2 : BIGF));
        ((float4*)(aug + 2 * H))[col] = f4scale(a3, 1.0f / (c3 > 0 ? (float)c3 : BIGF));
        ((float4*)(aug + 3 * H))[col] = f4scale(a4, 1.0f / (c4 > 0 ? (float)c4 : BIGF));
        ((float4*)(aug + 4 * H))[col] = f4scale(a5, 1.0f / (c5 > 0 ? (float)c5 : BIGF));
        ((float4*)paper)[col]         = f4scale(t,  1.0f / (ct > 0 ? (float)ct : BIGF));

        if (col == 0) {
            augmask[0] = c1 > 0 ? 1.0f : 0.0f;
            augmask[1] = c2 > 0 ? 1.0f : 0.0f;
            augmask[2] = c3 > 0 ? 1.0f : 0.0f;
            augmask[3] = c4 > 0 ? 1.0f : 0.0f;
            augmask[4] = c5 > 0 ? 1.0f : 0.0f;
            mask2[0]   = ct > 0 ? 1.0f : 0.0f;
        }
    }
}

extern "C" void kernel_launch(void* const* d_in, const int* in_sizes, int n_in,
                              void* d_out, int out_size, void* d_ws, size_t ws_size,
                              hipStream_t stream) {
    const float* tar_state = (const float*)d_in[0];
    const int*   tar_func  = (const int*)d_in[1];
    const float* ref_state = (const float*)d_in[2];
    const int*   ref_func  = (const int*)d_in[3];
    float* out = (float*)d_out;

    if (ws_size >= WS_NEED) {
        float* wsum = (float*)d_ws;
        int*   wcnt = (int*)((char*)d_ws + WCNT_OFF_B);
        emenc_stage1<<<NBLK1, 256, 0, stream>>>(tar_state, tar_func,
                                                ref_state, ref_func, wsum, wcnt);
        emenc_stage2<<<264 * 6, 128, 0, stream>>>(wsum, wcnt, out);
    } else {
        emenc_single<<<264, 256, 0, stream>>>(tar_state, tar_func,
                                              ref_state, ref_func, out);
    }
}

// Round 2
// 207.199 us; speedup vs baseline: 1.0035x; 1.0025x over previous
//
#include <hip/hip_runtime.h>

// Shapes: tarsent [8,512,512] f32, tar_func [8,512] i32,
//         refsent [8,32,256,512] f32, ref_func [8,32,256] i32.
// Output flat-concat f32 (masks as 0.0/1.0):
//   tar_aug[8,5,512]@0  tar_aug_mask[8,5]@20480  ref_aug[8,32,5,512]@20520
//   ref_aug_mask[8,32,5]@675880  tarpaper[8,512]@677160  tar_mask2[8]@681256
//   refpaper[8,32,512]@681264  ref_mask2[8,32]@812336   total 812592
//
// Single fused kernel, NO WORKSPACE USE. The 512 MiB workspace re-poison
// fills (~2x78us) dominated the timed graph; columns of the masked means
// are independent, so each segment is split across 4 column-slice blocks
// (counts recomputed per block via wave ballots) -- no cross-block
// reduction, no wsum round-trip, no stage-2 launch.

#define H       512
#define NL      5
#define BIGF    1e11f

#define OFF_TAR_AUG       0
#define OFF_TAR_AUG_MASK  20480
#define OFF_REF_AUG       20520
#define OFF_REF_AUG_MASK  675880
#define OFF_TARPAPER      677160
#define OFF_TAR_MASK2     681256
#define OFF_REFPAPER      681264
#define OFF_REF_MASK2     812336

#define NSEG_REF 256       // 8*32 ref docs
#define NSEG     264       // + 8 tar batches
#define NSLICE   4         // column slices per segment
#define SLICE_F  128       // floats per slice
#define SLICE_V  32        // float4 per slice
#define NPHASE   8         // row phases (256 threads / 32 cols)
#define SMAX     512

__device__ inline float4 f4add(float4 a, float4 b) {
    a.x += b.x; a.y += b.y; a.z += b.z; a.w += b.w; return a;
}
__device__ inline float4 f4scale(float4 a, float s) {
    a.x *= s; a.y *= s; a.z *= s; a.w *= s; return a;
}
__device__ inline float4 f4fma(float w, float4 v, float4 a) {
    a.x = fmaf(w, v.x, a.x); a.y = fmaf(w, v.y, a.y);
    a.z = fmaf(w, v.z, a.z); a.w = fmaf(w, v.w, a.w); return a;
}

__global__ __launch_bounds__(256) void emenc_fused(
    const float* __restrict__ tar_state, const int* __restrict__ tar_func,
    const float* __restrict__ ref_state, const int* __restrict__ ref_func,
    float* __restrict__ out)
{
    __shared__ int    crow[SMAX];                    // row | label<<16, compacted
    __shared__ float4 spart[NPHASE][NL][SLICE_V];    // 20 KB phase combine
    __shared__ int    scnt5[NL];
    __shared__ int    sm;

    const int b     = blockIdx.x;
    const int seg   = b >> 2;
    const int slice = b & 3;

    const float* state;
    const int*   func;
    int S;
    float *aug, *augmask, *paper, *mask2;
    if (seg < NSEG_REF) {
        state   = ref_state + (size_t)seg * 256 * H;
        func    = ref_func  + seg * 256;
        S       = 256;
        aug     = out + OFF_REF_AUG      + (size_t)seg * NL * H;
        augmask = out + OFF_REF_AUG_MASK + seg * NL;
        paper   = out + OFF_REFPAPER     + (size_t)seg * H;
        mask2   = out + OFF_REF_MASK2    + seg;
    } else {
        const int q = seg - NSEG_REF;
        state   = tar_state + (size_t)q * 512 * H;
        func    = tar_func  + q * 512;
        S       = 512;
        aug     = out + OFF_TAR_AUG      + (size_t)q * NL * H;
        augmask = out + OFF_TAR_AUG_MASK + q * NL;
        paper   = out + OFF_TARPAPER     + (size_t)q * H;
        mask2   = out + OFF_TAR_MASK2    + q;
    }

    const int tid = threadIdx.x;

    // Wave 0: ballot-compact non-pad rows + per-label counts, 64 rows/pass.
    if (tid < 64) {
        int cbase = 0;
        int c1 = 0, c2 = 0, c3 = 0, c4 = 0, c5 = 0;
        for (int s = tid; s < S; s += 64) {
            const int l = func[s];
            const unsigned long long m1 = __ballot(l == 1);
            const unsigned long long m2 = __ballot(l == 2);
            const unsigned long long m3 = __ballot(l == 3);
            const unsigned long long m4 = __ballot(l == 4);
            const unsigned long long m5 = __ballot(l == 5);
            const unsigned long long mz = __ballot(l != 0);
            if (l != 0) {
                const int pos = cbase +
                    (int)__popcll(mz & ((1ull << tid) - 1ull));
                crow[pos] = s | (l << 16);
            }
            cbase += (int)__popcll(mz);
            c1 += (int)__popcll(m1); c2 += (int)__popcll(m2);
            c3 += (int)__popcll(m3); c4 += (int)__popcll(m4);
            c5 += (int)__popcll(m5);
        }
        if (tid == 0) {
            scnt5[0] = c1; scnt5[1] = c2; scnt5[2] = c3;
            scnt5[3] = c4; scnt5[4] = c5;
            sm = cbase;
        }
    }
    __syncthreads();

    const int m     = sm;                 // non-pad rows in this segment
    const int col   = tid & (SLICE_V - 1);
    const int phase = tid >> 5;           // 0..7
    const float* sp = state + slice * SLICE_F;

    float4 a1 = {0,0,0,0}, a2 = {0,0,0,0}, a3 = {0,0,0,0},
           a4 = {0,0,0,0}, a5 = {0,0,0,0};

    // Direct-global streaming over compacted rows; each half-wave reads a
    // contiguous 512 B row-slice. Unroll keeps 4 loads in flight/thread.
    #pragma unroll 4
    for (int r = phase; r < m; r += NPHASE) {
        const int rc  = crow[r];
        const int row = rc & 0xffff;
        const int l   = rc >> 16;
        const float4 v = ((const float4*)(sp + ((size_t)row << 9)))[col];
        a1 = f4fma((l == 1) ? 1.0f : 0.0f, v, a1);
        a2 = f4fma((l == 2) ? 1.0f : 0.0f, v, a2);
        a3 = f4fma((l == 3) ? 1.0f : 0.0f, v, a3);
        a4 = f4fma((l == 4) ? 1.0f : 0.0f, v, a4);
        a5 = f4fma((l == 5) ? 1.0f : 0.0f, v, a5);
    }

    spart[phase][0][col] = a1;
    spart[phase][1][col] = a2;
    spart[phase][2][col] = a3;
    spart[phase][3][col] = a4;
    spart[phase][4][col] = a5;
    __syncthreads();

    // First 32 threads: combine 8 phases, scale, write this column slice.
    if (tid < SLICE_V) {
        float4 s1 = {0,0,0,0}, s2 = {0,0,0,0}, s3 = {0,0,0,0},
               s4 = {0,0,0,0}, s5 = {0,0,0,0};
        #pragma unroll
        for (int p = 0; p < NPHASE; ++p) {
            s1 = f4add(s1, spart[p][0][tid]);
            s2 = f4add(s2, spart[p][1][tid]);
            s3 = f4add(s3, spart[p][2][tid]);
            s4 = f4add(s4, spart[p][3][tid]);
            s5 = f4add(s5, spart[p][4][tid]);
        }
        const int c1 = scnt5[0], c2 = scnt5[1], c3 = scnt5[2],
                  c4 = scnt5[3], c5 = scnt5[4];
        const float4 t  = f4add(f4add(f4add(s1, s2), f4add(s3, s4)), s5);
        const int    ct = c1 + c2 + c3 + c4 + c5;

        const int cbase = slice * SLICE_F;
        ((float4*)(aug + 0 * H + cbase))[tid] =
            f4scale(s1, 1.0f / (c1 > 0 ? (float)c1 : BIGF));
        ((float4*)(aug + 1 * H + cbase))[tid] =
            f4scale(s2, 1.0f / (c2 > 0 ? (float)c2 : BIGF));
        ((float4*)(aug + 2 * H + cbase))[tid] =
            f4scale(s3, 1.0f / (c3 > 0 ? (float)c3 : BIGF));
        ((float4*)(aug + 3 * H + cbase))[tid] =
            f4scale(s4, 1.0f / (c4 > 0 ? (float)c4 : BIGF));
        ((float4*)(aug + 4 * H + cbase))[tid] =
            f4scale(s5, 1.0f / (c5 > 0 ? (float)c5 : BIGF));
        ((float4*)(paper + cbase))[tid] =
            f4scale(t, 1.0f / (ct > 0 ? (float)ct : BIGF));

        if (slice == 0 && tid == 0) {
            augmask[0] = c1 > 0 ? 1.0f : 0.0f;
            augmask[1] = c2 > 0 ? 1.0f : 0.0f;
            augmask[2] = c3 > 0 ? 1.0f : 0.0f;
            augmask[3] = c4 > 0 ? 1.0f : 0.0f;
            augmask[4] = c5 > 0 ? 1.0f : 0.0f;
            mask2[0]   = ct > 0 ? 1.0f : 0.0f;
        }
    }
}

extern "C" void kernel_launch(void* const* d_in, const int* in_sizes, int n_in,
                              void* d_out, int out_size, void* d_ws, size_t ws_size,
                              hipStream_t stream) {
    const float* tar_state = (const float*)d_in[0];
    const int*   tar_func  = (const int*)d_in[1];
    const float* ref_state = (const float*)d_in[2];
    const int*   ref_func  = (const int*)d_in[3];
    float* out = (float*)d_out;
    (void)d_ws; (void)ws_size;   // deliberately unused: avoid ws re-poison cost

    emenc_fused<<<NSEG * NSLICE, 256, 0, stream>>>(tar_state, tar_func,
                                                   ref_state, ref_func, out);
}